// Round 1
// baseline (966.837 us; speedup 1.0000x reference)
//
#include <hip/hip_runtime.h>

#define NPTS 8192
#define NCH 8
#define STRIDE 6144
#define TOTAL 51200
#define FADE 1228
#define SEG 16
#define SEGLEN 512   // NPTS / SEG

// ---------------------------------------------------------------------------
// copy chunks[0] -> final[0]
__global__ void k_copy0(const float* __restrict__ chunks, float* __restrict__ fin) {
    int i = blockIdx.x * 256 + threadIdx.x;           // 0..24575
    if (i < NPTS * 3) fin[i] = chunks[i];
}

// ---------------------------------------------------------------------------
// partial argmin over a 512-candidate segment.
// d2 = (pp + cc) - 2*g, g = fma(p2,c2, fma(p1,c1, p0*c0))  (Eigen dot semantics)
// pp/cc = (x*x + y*y) + z*z (mul + sequential add, no fma)
__global__ void k_argmin_part(const float* __restrict__ P, const float* __restrict__ C,
                              float* __restrict__ pm_d, int* __restrict__ pm_k) {
#pragma clang fp contract(off)
    __shared__ float4 sh[SEGLEN];
    int tid = threadIdx.x;
    int k0 = blockIdx.y * SEGLEN;
    for (int t = tid; t < SEGLEN; t += 256) {
        int k = k0 + t;
        float x = C[k * 3 + 0], y = C[k * 3 + 1], z = C[k * 3 + 2];
        float cc = (x * x + y * y) + z * z;
        sh[t] = make_float4(x, y, z, cc);
    }
    __syncthreads();
    int j = blockIdx.x * 256 + tid;
    float p0 = P[j * 3 + 0], p1 = P[j * 3 + 1], p2 = P[j * 3 + 2];
    float pp = (p0 * p0 + p1 * p1) + p2 * p2;
    float best = 3.4e38f;
    int bk = k0;
    for (int t = 0; t < SEGLEN; ++t) {
        float4 f = sh[t];
        float g = __builtin_fmaf(p2, f.z, __builtin_fmaf(p1, f.y, p0 * f.x));
        float d = (pp + f.w) - 2.0f * g;
        if (d < best) { best = d; bk = k0 + t; }   // strict <: first (lowest k) wins ties
    }
    pm_d[j * SEG + blockIdx.y] = best;
    pm_k[j * SEG + blockIdx.y] = bk;
}

// merge segment partials (ascending segment order => lowest index wins exact ties)
__global__ void k_argmin_merge(const float* __restrict__ pm_d, const int* __restrict__ pm_k,
                               int* __restrict__ mi, int* __restrict__ jmax) {
    int j = blockIdx.x * 256 + threadIdx.x;
    float best = pm_d[j * SEG];
    int bk = pm_k[j * SEG];
    for (int s = 1; s < SEG; ++s) {
        float d = pm_d[j * SEG + s];
        if (d < best) { best = d; bk = pm_k[j * SEG + s]; }
    }
    mi[j] = bk;
    jmax[j] = -1;    // init scatter-argmax buffer for this pair
}

// ---------------------------------------------------------------------------
// weight predictor MLP (1x1 convs) + fused combine + scatter argmax over j
__global__ void k_wp_fused(const float* __restrict__ P, const float* __restrict__ C,
                           const int* __restrict__ mi,
                           const float* __restrict__ w1, const float* __restrict__ b1,
                           const float* __restrict__ w2, const float* __restrict__ b2,
                           const float* __restrict__ w3, const float* __restrict__ b3,
                           float* __restrict__ fused, int* __restrict__ jmax) {
#pragma clang fp contract(off)
    int j = blockIdx.x * 256 + threadIdx.x;
    float x[6];
    x[0] = P[j * 3 + 0]; x[1] = P[j * 3 + 1]; x[2] = P[j * 3 + 2];
    int m = mi[j];
    x[3] = C[m * 3 + 0]; x[4] = C[m * 3 + 1]; x[5] = C[m * 3 + 2];

    float h1[32];
    for (int o = 0; o < 32; ++o) {
        float acc = 0.0f;
        for (int ci = 0; ci < 6; ++ci) acc = __builtin_fmaf(x[ci], w1[o * 6 + ci], acc);
        h1[o] = fmaxf(acc + b1[o], 0.0f);
    }
    float h2[16];
    for (int o = 0; o < 16; ++o) {
        float acc = 0.0f;
        for (int ci = 0; ci < 32; ++ci) acc = __builtin_fmaf(h1[ci], w2[o * 32 + ci], acc);
        h2[o] = fmaxf(acc + b2[o], 0.0f);
    }
    float acc = 0.0f;
    for (int ci = 0; ci < 16; ++ci) acc = __builtin_fmaf(h2[ci], w3[ci], acc);
    float z = acc + b3[0];
    float w = 1.0f / (1.0f + expf(-z));
    float omw = 1.0f - w;
    for (int e = 0; e < 3; ++e) {
        float t1 = w * x[e];
        float t2 = omw * x[3 + e];
        fused[e * NPTS + j] = t1 + t2;     // channel-major [3][N] == fused.T
    }
    atomicMax(&jmax[m], j);                // last-write-wins == max-j-wins
}

// ---------------------------------------------------------------------------
// smoother conv layer 1: 3 -> 32, K=5, pad=2, relu. in: [3][N] -> out: [32][N]
__global__ void k_conv1(const float* __restrict__ in, const float* __restrict__ w,
                        const float* __restrict__ b, float* __restrict__ out) {
#pragma clang fp contract(off)
    __shared__ float sh[3 * 260];
    int tid = threadIdx.x;
    int base = blockIdx.x * 256;
    for (int li = tid; li < 3 * 260; li += 256) {
        int ci = li / 260, t = base - 2 + (li % 260);
        sh[li] = (t >= 0 && t < NPTS) ? in[ci * NPTS + t] : 0.0f;
    }
    __syncthreads();
    int pos = base + tid;
    int co0 = blockIdx.y * 8;
    for (int co = co0; co < co0 + 8; ++co) {
        float acc = 0.0f;
        for (int k = 0; k < 5; ++k)
            for (int ci = 0; ci < 3; ++ci)
                acc = __builtin_fmaf(sh[ci * 260 + tid + k], w[(co * 3 + ci) * 5 + k], acc);
        out[co * NPTS + pos] = fmaxf(acc + b[co], 0.0f);
    }
}

// layer 2: 32 -> 32, K=5, pad=2, relu
__global__ void k_conv2(const float* __restrict__ in, const float* __restrict__ w,
                        const float* __restrict__ b, float* __restrict__ out) {
#pragma clang fp contract(off)
    __shared__ float sh[32 * 260];
    int tid = threadIdx.x;
    int base = blockIdx.x * 256;
    for (int li = tid; li < 32 * 260; li += 256) {
        int ci = li / 260, t = base - 2 + (li % 260);
        sh[ci * 260 + (li % 260)] = (t >= 0 && t < NPTS) ? in[ci * NPTS + t] : 0.0f;
    }
    __syncthreads();
    int pos = base + tid;
    int co0 = blockIdx.y * 4;
    for (int co = co0; co < co0 + 4; ++co) {
        float acc = 0.0f;
        for (int k = 0; k < 5; ++k)
            for (int ci = 0; ci < 32; ++ci)
                acc = __builtin_fmaf(sh[ci * 260 + tid + k], w[(co * 32 + ci) * 5 + k], acc);
        out[co * NPTS + pos] = fmaxf(acc + b[co], 0.0f);
    }
}

// layer 3: 32 -> 3, K=5, pad=2, no relu; writes point-major [N][3] (sm)
__global__ void k_conv3(const float* __restrict__ in, const float* __restrict__ w,
                        const float* __restrict__ b, float* __restrict__ outPM) {
#pragma clang fp contract(off)
    __shared__ float sh[32 * 260];
    int tid = threadIdx.x;
    int base = blockIdx.x * 256;
    for (int li = tid; li < 32 * 260; li += 256) {
        int ci = li / 260, t = base - 2 + (li % 260);
        sh[ci * 260 + (li % 260)] = (t >= 0 && t < NPTS) ? in[ci * NPTS + t] : 0.0f;
    }
    __syncthreads();
    int pos = base + tid;
    for (int co = 0; co < 3; ++co) {
        float acc = 0.0f;
        for (int k = 0; k < 5; ++k)
            for (int ci = 0; ci < 32; ++ci)
                acc = __builtin_fmaf(sh[ci * 260 + tid + k], w[(co * 32 + ci) * 5 + k], acc);
        outPM[pos * 3 + co] = acc + b[co];
    }
}

// ---------------------------------------------------------------------------
// c_new[k] = (jmax[k] >= 0) ? sm[jmax[k]] : c[k]
__global__ void k_scatter(const int* __restrict__ jmax, const float* __restrict__ sm,
                          const float* __restrict__ C, float* __restrict__ outPM) {
    int k = blockIdx.x * 256 + threadIdx.x;
    int jm = jmax[k];
    if (jm >= 0) {
        outPM[k * 3 + 0] = sm[jm * 3 + 0];
        outPM[k * 3 + 1] = sm[jm * 3 + 1];
        outPM[k * 3 + 2] = sm[jm * 3 + 2];
    } else {
        outPM[k * 3 + 0] = C[k * 3 + 0];
        outPM[k * 3 + 1] = C[k * 3 + 1];
        outPM[k * 3 + 2] = C[k * 3 + 2];
    }
}

// ---------------------------------------------------------------------------
// fade-weighted merge (ascending chunk order matches scatter-add order)
__global__ void k_merge(const float* __restrict__ fin, float* __restrict__ out) {
#pragma clang fp contract(off)
    int pos = blockIdx.x * 256 + threadIdx.x;
    if (pos >= TOTAL) return;
    int imax = pos / STRIDE; if (imax > NCH - 1) imax = NCH - 1;
    int imin = (pos >= NPTS) ? ((pos - NPTS) / STRIDE + 1) : 0;
    float a0 = 0.0f, a1 = 0.0f, a2 = 0.0f, wsum = 0.0f;
    const float kstep = 0.9f / 1227.0f;
    for (int i = imin; i <= imax; ++i) {
        int t = pos - i * STRIDE;
        float cw;
        if (t < FADE)                cw = 0.1f + (float)t * kstep;
        else if (t >= NPTS - FADE)   cw = 1.0f - (float)(t - (NPTS - FADE)) * kstep;
        else                         cw = 1.0f;
        const float* v = fin + (i * NPTS + t) * 3;
        a0 += cw * v[0];
        a1 += cw * v[1];
        a2 += cw * v[2];
        wsum += cw;
    }
    float wm = fmaxf(wsum, 1e-8f);
    out[pos * 3 + 0] = a0 / wm;
    out[pos * 3 + 1] = a1 / wm;
    out[pos * 3 + 2] = a2 / wm;
}

// ---------------------------------------------------------------------------
extern "C" void kernel_launch(void* const* d_in, const int* in_sizes, int n_in,
                              void* d_out, int out_size, void* d_ws, size_t ws_size,
                              hipStream_t stream) {
    const float* chunks = (const float*)d_in[0];
    const float* bs_w1 = (const float*)d_in[1];
    const float* bs_b1 = (const float*)d_in[2];
    const float* bs_w2 = (const float*)d_in[3];
    const float* bs_b2 = (const float*)d_in[4];
    const float* bs_w3 = (const float*)d_in[5];
    const float* bs_b3 = (const float*)d_in[6];
    const float* wp_w1 = (const float*)d_in[7];
    const float* wp_b1 = (const float*)d_in[8];
    const float* wp_w2 = (const float*)d_in[9];
    const float* wp_b2 = (const float*)d_in[10];
    const float* wp_w3 = (const float*)d_in[11];
    const float* wp_b3 = (const float*)d_in[12];

    float* ws = (float*)d_ws;
    float* fin   = ws;                        // 8 * 8192 * 3   = 196608 f32
    float* h1    = fin + NCH * NPTS * 3;      // 32 * 8192      = 262144 f32
    float* h2    = h1 + 32 * NPTS;            // 32 * 8192      = 262144 f32
    float* fused = h2 + 32 * NPTS;            // 3 * 8192       = 24576  f32
    float* pm_d  = fused + 3 * NPTS;          // 8192 * 16      = 131072 f32
    int*   pm_k  = (int*)(pm_d + NPTS * SEG); // 8192 * 16      = 131072 i32
    int*   mi    = pm_k + NPTS * SEG;         // 8192 i32
    int*   jmax  = mi + NPTS;                 // 8192 i32
    // total ~4.1 MB of ws

    k_copy0<<<96, 256, 0, stream>>>(chunks, fin);

    for (int i = 1; i < NCH; ++i) {
        const float* C = chunks + i * NPTS * 3;
        float* P  = fin + (i - 1) * NPTS * 3;   // c_new from previous pair (or chunks[0])
        float* Pn = fin + i * NPTS * 3;

        k_argmin_part<<<dim3(32, SEG), 256, 0, stream>>>(P, C, pm_d, pm_k);
        k_argmin_merge<<<32, 256, 0, stream>>>(pm_d, pm_k, mi, jmax);
        k_wp_fused<<<32, 256, 0, stream>>>(P, C, mi, wp_w1, wp_b1, wp_w2, wp_b2,
                                           wp_w3, wp_b3, fused, jmax);
        k_conv1<<<dim3(32, 4), 256, 0, stream>>>(fused, bs_w1, bs_b1, h1);
        k_conv2<<<dim3(32, 8), 256, 0, stream>>>(h1, bs_w2, bs_b2, h2);
        k_conv3<<<32, 256, 0, stream>>>(h2, bs_w3, bs_b3, P);   // sm overwrites final[i-1]
        k_scatter<<<32, 256, 0, stream>>>(jmax, P, C, Pn);      // c_new -> final[i]
    }

    k_merge<<<200, 256, 0, stream>>>(fin, (float*)d_out);
}

// Round 2
// 575.898 us; speedup vs baseline: 1.6788x; 1.6788x over previous
//
#include <hip/hip_runtime.h>

#define NPTS 8192
#define NCH 8
#define STRIDE 6144
#define TOTAL 51200
#define FADE 1228
#define SEG 32
#define SEGLEN 256   // NPTS / SEG
#define JB 4         // j's per thread in argmin

// ---------------------------------------------------------------------------
__global__ void k_init_jmax(int* __restrict__ jmax_all) {
    int i = blockIdx.x * 256 + threadIdx.x;        // 7 * 8192 = 57344
    if (i < (NCH - 1) * NPTS) jmax_all[i] = -1;
}

__global__ void k_copy0(const float* __restrict__ chunks, float* __restrict__ fin) {
    int i = blockIdx.x * 256 + threadIdx.x;        // 0..24575
    if (i < NPTS * 3) fin[i] = chunks[i];
}

// ---------------------------------------------------------------------------
// partial argmin over a 256-candidate segment; each thread owns 4 consecutive j.
// d2 math bit-identical to round 1: g = fma(p2,cz, fma(p1,cy, p0*cx));
// d = (pp + cc) - 2*g; pp/cc = (x*x + y*y) + z*z; strict < , ascending k.
__global__ void k_argmin_part(const float* __restrict__ P, const float* __restrict__ C,
                              float* __restrict__ pm_d, int* __restrict__ pm_k) {
#pragma clang fp contract(off)
    __shared__ float4 sh[SEGLEN];
    int tid = threadIdx.x;
    int k0 = blockIdx.y * SEGLEN;
    {
        int k = k0 + tid;
        float x = C[k * 3 + 0], y = C[k * 3 + 1], z = C[k * 3 + 2];
        float cc = (x * x + y * y) + z * z;
        sh[tid] = make_float4(x, y, z, cc);
    }
    __syncthreads();
    int j0 = blockIdx.x * (256 * JB) + tid * JB;
    const float4* Pv = (const float4*)(P + j0 * 3);   // 12 floats = 3 float4 (16B aligned)
    float4 a = Pv[0], b = Pv[1], c4 = Pv[2];
    float p0[JB] = {a.x, a.w, b.z, c4.y};
    float p1[JB] = {a.y, b.x, b.w, c4.z};
    float p2[JB] = {a.z, b.y, c4.x, c4.w};
    float pp[JB], best[JB];
    int bk[JB];
#pragma unroll
    for (int i = 0; i < JB; ++i) {
        pp[i] = (p0[i] * p0[i] + p1[i] * p1[i]) + p2[i] * p2[i];
        best[i] = 3.4e38f;
        bk[i] = k0;
    }
#pragma unroll 2
    for (int t = 0; t < SEGLEN; ++t) {
        float4 f = sh[t];
#pragma unroll
        for (int i = 0; i < JB; ++i) {
            float g = __builtin_fmaf(p2[i], f.z, __builtin_fmaf(p1[i], f.y, p0[i] * f.x));
            float d = (pp[i] + f.w) - 2.0f * g;
            if (d < best[i]) { best[i] = d; bk[i] = k0 + t; }
        }
    }
#pragma unroll
    for (int i = 0; i < JB; ++i) {
        pm_d[(j0 + i) * SEG + blockIdx.y] = best[i];
        pm_k[(j0 + i) * SEG + blockIdx.y] = bk[i];
    }
}

// ---------------------------------------------------------------------------
// merge segment partials (ascending) + weight-predictor MLP + fused + atomicMax
__global__ void k_mid(const float* __restrict__ P, const float* __restrict__ C,
                      const float* __restrict__ pm_d, const int* __restrict__ pm_k,
                      const float* __restrict__ w1, const float* __restrict__ b1,
                      const float* __restrict__ w2, const float* __restrict__ b2,
                      const float* __restrict__ w3, const float* __restrict__ b3,
                      float* __restrict__ fused, int* __restrict__ jmax) {
#pragma clang fp contract(off)
    int j = blockIdx.x * 256 + threadIdx.x;
    // merge 32 partials ascending, strict <  (identical winner to full ascending scan)
    const float4* dv = (const float4*)(pm_d + j * SEG);
    const int4*   kv = (const int4*)(pm_k + j * SEG);
    float best = 3.4e38f;
    int bk = 0;
#pragma unroll
    for (int s = 0; s < SEG / 4; ++s) {
        float4 d4 = dv[s];
        int4 k4 = kv[s];
        if (d4.x < best) { best = d4.x; bk = k4.x; }
        if (d4.y < best) { best = d4.y; bk = k4.y; }
        if (d4.z < best) { best = d4.z; bk = k4.z; }
        if (d4.w < best) { best = d4.w; bk = k4.w; }
    }
    int m = bk;
    float x[6];
    x[0] = P[j * 3 + 0]; x[1] = P[j * 3 + 1]; x[2] = P[j * 3 + 2];
    x[3] = C[m * 3 + 0]; x[4] = C[m * 3 + 1]; x[5] = C[m * 3 + 2];

    float h1[32];
    for (int o = 0; o < 32; ++o) {
        float acc = 0.0f;
        for (int ci = 0; ci < 6; ++ci) acc = __builtin_fmaf(x[ci], w1[o * 6 + ci], acc);
        h1[o] = fmaxf(acc + b1[o], 0.0f);
    }
    float h2[16];
    for (int o = 0; o < 16; ++o) {
        float acc = 0.0f;
        for (int ci = 0; ci < 32; ++ci) acc = __builtin_fmaf(h1[ci], w2[o * 32 + ci], acc);
        h2[o] = fmaxf(acc + b2[o], 0.0f);
    }
    float acc = 0.0f;
    for (int ci = 0; ci < 16; ++ci) acc = __builtin_fmaf(h2[ci], w3[ci], acc);
    float z = acc + b3[0];
    float w = 1.0f / (1.0f + expf(-z));
    float omw = 1.0f - w;
    for (int e = 0; e < 3; ++e) {
        float t1 = w * x[e];
        float t2 = omw * x[3 + e];
        fused[e * NPTS + j] = t1 + t2;
    }
    atomicMax(&jmax[m], j);
}

// ---------------------------------------------------------------------------
// fused boundary smoother: conv1(3->32,relu) -> conv2(32->32,relu) -> conv3(32->3)
// block = 32 output positions, halo recompute; grid = 256 blocks.
// Per-output accumulation chains identical to round 1: k outer, ci inner, fma from 0.
#define S1 41   // H1 row stride (40 used)
#define S2 37   // H2 row stride (36 used)
__global__ __launch_bounds__(256) void k_smoother(const float* __restrict__ fused,
        const float* __restrict__ w1g, const float* __restrict__ b1g,
        const float* __restrict__ w2g, const float* __restrict__ b2g,
        const float* __restrict__ w3g, const float* __restrict__ b3g,
        float* __restrict__ sm) {
#pragma clang fp contract(off)
    __shared__ float F[3][44];
    __shared__ float H1[32][S1];
    __shared__ float H2[32][S2];
    __shared__ float W2[5120];   // [ci][k][co] : [(ci*5+k)*32 + co]
    __shared__ float B2[32];
    int tid = threadIdx.x;
    int BASE = blockIdx.x * 32;

    // stage fused window [BASE-6, BASE+38)
    for (int li = tid; li < 132; li += 256) {
        int c = li / 44, i = li % 44;
        int t = BASE - 6 + i;
        F[c][i] = (t >= 0 && t < NPTS) ? fused[c * NPTS + t] : 0.0f;
    }
    // stage conv2 weights with [ci][k][co] transform
    for (int li = tid; li < 1280; li += 256) {
        float4 v = ((const float4*)w2g)[li];
        int base = li * 4;
#pragma unroll
        for (int u = 0; u < 4; ++u) {
            int idx = base + u;               // = (co*32+ci)*5+k
            int co = idx / 160;
            int r = idx - co * 160;
            int ci = r / 5;
            int k = r - ci * 5;
            W2[(ci * 5 + k) * 32 + co] = (&v.x)[u];
        }
    }
    if (tid < 32) B2[tid] = b2g[tid];
    __syncthreads();

    // ---- phase B: conv1 -> H1 on [BASE-4, BASE+36)  (40 positions) ----
    {
        int co = tid >> 3, pg = tid & 7;      // 32 co x 8 groups of 5 positions
        float wr[15];
#pragma unroll
        for (int q = 0; q < 15; ++q) wr[q] = w1g[co * 15 + q];
        float bias = b1g[co];
#pragma unroll
        for (int s = 0; s < 5; ++s) {
            int i = pg * 5 + s;               // 0..39
            int t = BASE - 4 + i;
            float acc = 0.0f;
#pragma unroll
            for (int k = 0; k < 5; ++k)
#pragma unroll
                for (int ci = 0; ci < 3; ++ci)
                    acc = __builtin_fmaf(F[ci][i + k], wr[ci * 5 + k], acc);
            H1[co][i] = (t >= 0 && t < NPTS) ? fmaxf(acc + bias, 0.0f) : 0.0f;
        }
    }
    __syncthreads();

    // ---- phase C: conv2 -> H2 on [BASE-2, BASE+34)  (36 positions) ----
    {
        int cq = tid & 7, pp = tid >> 3;      // 8 co-quads x 18 pos-pairs (tid<144 active)
        if (pp < 18) {
            int i2 = pp * 2;
            int co0 = cq * 4;
            float acc00 = 0.f, acc01 = 0.f, acc02 = 0.f, acc03 = 0.f;
            float acc10 = 0.f, acc11 = 0.f, acc12 = 0.f, acc13 = 0.f;
            for (int k = 0; k < 5; ++k) {
#pragma unroll
                for (int ci = 0; ci < 32; ++ci) {
                    float in0 = H1[ci][i2 + k];
                    float in1 = H1[ci][i2 + k + 1];
                    const float4 wv = *(const float4*)&W2[(ci * 5 + k) * 32 + co0];
                    acc00 = __builtin_fmaf(in0, wv.x, acc00);
                    acc01 = __builtin_fmaf(in0, wv.y, acc01);
                    acc02 = __builtin_fmaf(in0, wv.z, acc02);
                    acc03 = __builtin_fmaf(in0, wv.w, acc03);
                    acc10 = __builtin_fmaf(in1, wv.x, acc10);
                    acc11 = __builtin_fmaf(in1, wv.y, acc11);
                    acc12 = __builtin_fmaf(in1, wv.z, acc12);
                    acc13 = __builtin_fmaf(in1, wv.w, acc13);
                }
            }
            int t0 = BASE - 2 + i2, t1 = t0 + 1;
            bool ok0 = (t0 >= 0 && t0 < NPTS), ok1 = (t1 >= 0 && t1 < NPTS);
            H2[co0 + 0][i2]     = ok0 ? fmaxf(acc00 + B2[co0 + 0], 0.0f) : 0.0f;
            H2[co0 + 1][i2]     = ok0 ? fmaxf(acc01 + B2[co0 + 1], 0.0f) : 0.0f;
            H2[co0 + 2][i2]     = ok0 ? fmaxf(acc02 + B2[co0 + 2], 0.0f) : 0.0f;
            H2[co0 + 3][i2]     = ok0 ? fmaxf(acc03 + B2[co0 + 3], 0.0f) : 0.0f;
            H2[co0 + 0][i2 + 1] = ok1 ? fmaxf(acc10 + B2[co0 + 0], 0.0f) : 0.0f;
            H2[co0 + 1][i2 + 1] = ok1 ? fmaxf(acc11 + B2[co0 + 1], 0.0f) : 0.0f;
            H2[co0 + 2][i2 + 1] = ok1 ? fmaxf(acc12 + B2[co0 + 2], 0.0f) : 0.0f;
            H2[co0 + 3][i2 + 1] = ok1 ? fmaxf(acc13 + B2[co0 + 3], 0.0f) : 0.0f;
        }
    }
    __syncthreads();

    // ---- phase D: conv3 -> sm[BASE..BASE+32), point-major [N][3] ----
    if (tid < 96) {
        int co = tid >> 5, p = tid & 31;
        float wr[160];
        const float4* w3v = (const float4*)(w3g + co * 160);
#pragma unroll
        for (int q = 0; q < 40; ++q) {
            float4 v = w3v[q];
            wr[q * 4 + 0] = v.x; wr[q * 4 + 1] = v.y;
            wr[q * 4 + 2] = v.z; wr[q * 4 + 3] = v.w;
        }
        float acc = 0.0f;
#pragma unroll
        for (int k = 0; k < 5; ++k)
#pragma unroll
            for (int ci = 0; ci < 32; ++ci)
                acc = __builtin_fmaf(H2[ci][p + k], wr[ci * 5 + k], acc);
        sm[(BASE + p) * 3 + co] = acc + b3g[co];
    }
}

// ---------------------------------------------------------------------------
__global__ void k_scatter(const int* __restrict__ jmax, const float* __restrict__ sm,
                          const float* __restrict__ C, float* __restrict__ outPM) {
    int k = blockIdx.x * 256 + threadIdx.x;
    int jm = jmax[k];
    if (jm >= 0) {
        outPM[k * 3 + 0] = sm[jm * 3 + 0];
        outPM[k * 3 + 1] = sm[jm * 3 + 1];
        outPM[k * 3 + 2] = sm[jm * 3 + 2];
    } else {
        outPM[k * 3 + 0] = C[k * 3 + 0];
        outPM[k * 3 + 1] = C[k * 3 + 1];
        outPM[k * 3 + 2] = C[k * 3 + 2];
    }
}

// ---------------------------------------------------------------------------
__global__ void k_merge(const float* __restrict__ fin, float* __restrict__ out) {
#pragma clang fp contract(off)
    int pos = blockIdx.x * 256 + threadIdx.x;
    if (pos >= TOTAL) return;
    int imax = pos / STRIDE; if (imax > NCH - 1) imax = NCH - 1;
    int imin = (pos >= NPTS) ? ((pos - NPTS) / STRIDE + 1) : 0;
    float a0 = 0.0f, a1 = 0.0f, a2 = 0.0f, wsum = 0.0f;
    const float kstep = 0.9f / 1227.0f;
    for (int i = imin; i <= imax; ++i) {
        int t = pos - i * STRIDE;
        float cw;
        if (t < FADE)                cw = 0.1f + (float)t * kstep;
        else if (t >= NPTS - FADE)   cw = 1.0f - (float)(t - (NPTS - FADE)) * kstep;
        else                         cw = 1.0f;
        const float* v = fin + (i * NPTS + t) * 3;
        a0 += cw * v[0];
        a1 += cw * v[1];
        a2 += cw * v[2];
        wsum += cw;
    }
    float wm = fmaxf(wsum, 1e-8f);
    out[pos * 3 + 0] = a0 / wm;
    out[pos * 3 + 1] = a1 / wm;
    out[pos * 3 + 2] = a2 / wm;
}

// ---------------------------------------------------------------------------
extern "C" void kernel_launch(void* const* d_in, const int* in_sizes, int n_in,
                              void* d_out, int out_size, void* d_ws, size_t ws_size,
                              hipStream_t stream) {
    const float* chunks = (const float*)d_in[0];
    const float* bs_w1 = (const float*)d_in[1];
    const float* bs_b1 = (const float*)d_in[2];
    const float* bs_w2 = (const float*)d_in[3];
    const float* bs_b2 = (const float*)d_in[4];
    const float* bs_w3 = (const float*)d_in[5];
    const float* bs_b3 = (const float*)d_in[6];
    const float* wp_w1 = (const float*)d_in[7];
    const float* wp_b1 = (const float*)d_in[8];
    const float* wp_w2 = (const float*)d_in[9];
    const float* wp_b2 = (const float*)d_in[10];
    const float* wp_w3 = (const float*)d_in[11];
    const float* wp_b3 = (const float*)d_in[12];

    float* ws = (float*)d_ws;
    float* fin      = ws;                          // 8*8192*3 = 196608
    float* fused    = fin + NCH * NPTS * 3;        // 3*8192   = 24576
    float* pm_d     = fused + 3 * NPTS;            // 8192*32  = 262144
    int*   pm_k     = (int*)(pm_d + NPTS * SEG);   // 262144
    int*   jmax_all = pm_k + NPTS * SEG;           // 7*8192   = 57344
    // total ~3.2 MB

    k_init_jmax<<<224, 256, 0, stream>>>(jmax_all);
    k_copy0<<<96, 256, 0, stream>>>(chunks, fin);

    for (int i = 1; i < NCH; ++i) {
        const float* C = chunks + i * NPTS * 3;
        float* P  = fin + (i - 1) * NPTS * 3;
        float* Pn = fin + i * NPTS * 3;
        int* jmax = jmax_all + (i - 1) * NPTS;

        k_argmin_part<<<dim3(NPTS / (256 * JB), SEG), 256, 0, stream>>>(P, C, pm_d, pm_k);
        k_mid<<<32, 256, 0, stream>>>(P, C, pm_d, pm_k, wp_w1, wp_b1, wp_w2, wp_b2,
                                      wp_w3, wp_b3, fused, jmax);
        k_smoother<<<256, 256, 0, stream>>>(fused, bs_w1, bs_b1, bs_w2, bs_b2,
                                            bs_w3, bs_b3, P);   // sm overwrites fin[i-1]
        k_scatter<<<32, 256, 0, stream>>>(jmax, P, C, Pn);
    }

    k_merge<<<200, 256, 0, stream>>>(fin, (float*)d_out);
}